// Round 2
// baseline (477.976 us; speedup 1.0000x reference)
//
#include <hip/hip_runtime.h>
#include <cstring>

// Scene splat, gather formulation v6.
// R1: 41M global atomics cap at 65 Gops/s -> gather inversion (994->519 us).
// R2/R4: ~308 us of dur_us is harness poison/restore (fixed floor); gather
//        ~165 us vs ~79 us traffic floor (164 MB cold read + 335 MB write).
// R5: channel-merge (5x MLP) was NEUTRAL -> not latency-bound on reads.
// R6 A/B: nt stores -> PLAIN stores (win). Writes terminate in L2/L3.
// R7: XCD-contiguous tile swizzle NEUTRAL. L3 is die-level shared, so
//   cross-XCD duplicate fetches / fragmented drains hit L3, not HBM.
//   Cross-block write aggregation is not the lever.
// R8 (this): tile reshape 64x64 -> 16x256. Per-block writes go from
//   320 scattered 256B row-segments to 80 row-segments of 1 KB (4x coarser
//   DRAM burst locality at drain); 16 tiles/tile-row cover full 16 KB frame
//   rows. Same NTILES, same bytes. Also: row-predicate once per entry,
//   higher active-lane fraction (16-row tile usually fully inside 64-row
//   patch vertically). Entries/tile ~2.0 -> ~3.1 (negligible list cost).
//   Predict: gather 165 -> ~115-130 us, total 476 -> ~425-440.

typedef float vf4 __attribute__((ext_vector_type(4)));

constexpr int C  = 5;
constexpr int H  = 4096;
constexpr int W  = 4096;
constexpr int N  = 2000;
constexpr int PH = 64;
constexpr int PW = 64;

constexpr int TH = 16;                  // tile height
constexpr int TW = 256;                 // tile width
constexpr int TX = W / TW;              // 16 tiles per row
constexpr int TY = H / TH;              // 256 tile rows
constexpr int NTILES = TX * TY;         // 4096 (same as v5)
constexpr int CAP    = 128;             // mean ~3.1 entries/tile; tail << 128

__global__ __launch_bounds__(256) void bin_patches(
    const int2* __restrict__ positions,
    int*        __restrict__ counts,    // [NTILES]
    int2*       __restrict__ lists)     // [NTILES][CAP] : {n, (py<<16)|px}
{
    int n = blockIdx.x * blockDim.x + threadIdx.x;
    if (n >= N) return;
    int2 p = positions[n];              // .x = row offset, .y = col offset
    int packed = (p.x << 16) | p.y;     // both < 4096, fit 16b
    int ty0 = p.x >> 4, ty1 = (p.x + PH - 1) >> 4;   // /TH : up to 5 tiles
    int tx0 = p.y >> 8, tx1 = (p.y + PW - 1) >> 8;   // /TW : 1-2 tiles
    for (int ty = ty0; ty <= ty1; ++ty)
        for (int tx = tx0; tx <= tx1; ++tx) {
            int tile = ty * TX + tx;
            int slot = atomicAdd(&counts[tile], 1);
            if (slot < CAP) lists[tile * CAP + slot] = make_int2(n, packed);
        }
}

__global__ __launch_bounds__(256) void gather_tiles(
    const float* __restrict__ patches,   // (N, C, PH, PW)
    const int*   __restrict__ counts,
    const int2*  __restrict__ lists,
    float*       __restrict__ out)       // (C, H, W)
{
    // Keep R7's bijective XCD-contiguous swizzle (neutral, theoretically
    // aligns same-frame-row tiles on one XCD's L2). NTILES % 8 == 0.
    int bid  = blockIdx.x;
    int tile = ((bid & 7) << 9) | (bid >> 3);

    int y0 = (tile >> 4) << 4;           // tile_y * TH
    int x0 = (tile & (TX - 1)) << 8;     // tile_x * TW
    int t  = threadIdx.x;
    int row  = t >> 4;                   // 0..15: thread's tile row
    int colb = (t & 15) << 2;            // base col; owns colb + 64*k, k=0..3

    vf4 acc[C][4] = {};                  // 80 VGPRs of accumulator

    int cnt = counts[tile];
    if (cnt > CAP) cnt = CAP;
    const int2* lst = lists + (size_t)tile * CAP;

    for (int i = 0; i < cnt; ++i) {
        int2 e = lst[i];                 // e.x = n, e.y = (py<<16)|px
        int py = e.y >> 16;
        int px = e.y & 0xffff;

        int pr = y0 - py + row;          // this thread's patch row
        if ((unsigned)pr >= (unsigned)PH) continue;

        const float* prow = patches + (size_t)e.x * (C * PH * PW) + pr * PW;
        int rx0 = x0 - px + colb;        // patch col of chunk k=0

        #pragma unroll
        for (int k = 0; k < 4; ++k) {
            int rxb = rx0 + 64 * k;
            if ((unsigned)rxb <= (unsigned)(PW - 4)) {
                #pragma unroll
                for (int c = 0; c < C; ++c) {     // 5 independent dwordx4s
                    vf4 v;
                    __builtin_memcpy(&v, prow + c * (PH * PW) + rxb, sizeof(vf4));
                    acc[c][k] += v;
                }
            } else if (rxb > -4 && rxb < PW) {    // straddles patch x-edge
                #pragma unroll
                for (int j = 0; j < 4; ++j) {
                    int pxx = rxb + j;
                    if ((unsigned)pxx < (unsigned)PW) {
                        #pragma unroll
                        for (int c = 0; c < C; ++c)
                            acc[c][k][j] += prow[c * (PH * PW) + pxx];
                    }
                }
            }
        }
    }

    // Writeback: PLAIN stores (R6 win). Each frame row gets 1 KB contiguous
    // from this block (4 x vf4 per thread-row); zero tiles write zeros
    // (replaces the full-frame memset).
    #pragma unroll
    for (int c = 0; c < C; ++c) {
        float* orow = out + ((size_t)c * H + y0 + row) * W + x0;
        #pragma unroll
        for (int k = 0; k < 4; ++k) {
            *(vf4*)(orow + colb + 64 * k) = acc[c][k];
        }
    }
}

extern "C" void kernel_launch(void* const* d_in, const int* in_sizes, int n_in,
                              void* d_out, int out_size, void* d_ws, size_t ws_size,
                              hipStream_t stream) {
    const float* patches   = (const float*)d_in[0];
    const int2*  positions = (const int2*)d_in[1];
    float*       out       = (float*)d_out;

    int*  counts = (int*)d_ws;                       // NTILES ints
    int2* lists  = (int2*)(counts + NTILES);         // NTILES*CAP int2 (4 MB)

    (void)hipMemsetAsync(counts, 0, NTILES * sizeof(int), stream);

    bin_patches<<<(N + 255) / 256, 256, 0, stream>>>(positions, counts, lists);

    gather_tiles<<<NTILES, 256, 0, stream>>>(patches, counts, lists, out);
}